// Round 3
// baseline (189.655 us; speedup 1.0000x reference)
//
#include <hip/hip_runtime.h>
#include <hip/hip_bf16.h>
#include <cfloat>
#include <cmath>

namespace {
constexpr int NB = 2;     // batch
constexpr int NN = 64;    // user inputs
constexpr int NC = 256;   // feature channels
constexpr int NK = 10;    // classes
constexpr float ALPHA = -1.0f / 18.0f;   // -0.5/sigma^2, sigma=3
constexpr int TMPL_FLOATS = 3 * NB * NC * NN;  // 98304 floats = 384 KiB
} // namespace

// load float input element i, runtime dtype (wave-uniform f32 flag)
__device__ __forceinline__ float ldf(const void* p, size_t i, bool f32) {
  return f32 ? ((const float*)p)[i]
             : __bfloat162float(((const __hip_bfloat16*)p)[i]);
}

// ---------------------------------------------------------------------------
// Kernel 0: detect whether float inputs are fp32 or bf16 (R1 evidence: fp32,
// but keep the runtime hedge — it costs ~2us and survives harness changes).
// ---------------------------------------------------------------------------
__global__ void detect_kernel(const unsigned short* __restrict__ x0w,
                              int* __restrict__ flag) {
  __shared__ int bad;
  if (threadIdx.x == 0) bad = 0;
  __syncthreads();
  int local = 0;
  for (int i = threadIdx.x; i < 2048; i += 256) {
    const unsigned e = (x0w[i] >> 7) & 0xFF;   // bf16 exponent field
    if (e >= 137) local = 1;                   // |v| >= 1024, inf, or NaN
  }
  if (local) atomicOr(&bad, 1);
  __syncthreads();
  if (threadIdx.x == 0) flag[0] = bad;         // 1 = fp32 inputs
}

// ---------------------------------------------------------------------------
// Kernel 1: per (level,b,n) template  tmpl[c] = sum_p h[p]*feat[c,p]
// h separable: ex[c]*ey[r] / (Sx*Sy + 1e-8); Gaussian support windowed
// (rel cutoff 1e-7, far below tolerance). Stored TRANSPOSED [lvl][b][c][n]
// so kernel 2 reads n-contiguous, wave-uniform rows.
// ---------------------------------------------------------------------------
__global__ __launch_bounds__(256) void tmpl_kernel(
    const void* __restrict__ x0, const void* __restrict__ x1,
    const void* __restrict__ x2, const void* __restrict__ centers,
    const int* __restrict__ idxp, const int* __restrict__ labels,
    const int* __restrict__ flag, float* __restrict__ tmpl_t) {
  const int bx  = blockIdx.x;          // 3*NB*NN = 384 blocks
  const int lvl = bx >> 7;
  const int b   = (bx >> 6) & 1;
  const int n   = bx & 63;
  const int W   = 64 >> lvl;           // 64,32,16
  const int HW  = W * W;
  const float s = (float)(8 << lvl);   // nearest-resize stride
  const void* feat = (lvl == 0) ? x0 : (lvl == 1) ? x1 : x2;
  const bool f32 = flag[0] != 0;

  __shared__ float ex[64], ey[64];
  __shared__ float sh_inv;
  __shared__ int   sh_win[4];

  const int t = threadIdx.x;
  const float cx = ldf(centers, (size_t)(b * NN + n) * 2 + 0, f32);
  const float cy = ldf(centers, (size_t)(b * NN + n) * 2 + 1, f32);

  if (t < W) {
    const float dx = (float)t * s + 0.5f - cx;
    const float dy = (float)t * s + 0.5f - cy;
    ex[t] = expf(ALPHA * dx * dx);
    ey[t] = expf(ALPHA * dy * dy);
  }
  __syncthreads();

  if (t == 0) {
    // int64 hedge: labels in [1,10]; if int64(LE), word[1]==0.
    const bool i64 = (labels[1] == 0);
    const int  m   = b * NN + n;
    const int  iv  = i64 ? idxp[2 * m] : idxp[m];
    float Sx = 0.f, Sy = 0.f;
    for (int i = 0; i < W; ++i) { Sx += ex[i]; Sy += ey[i]; }
    sh_inv = (iv != -1) ? 1.0f / (Sx * Sy + 1e-8f) : 0.0f;
    int cs = (int)floorf((cx - 0.5f) / s + 0.5f); cs = min(max(cs, 0), W - 1);
    int rs = (int)floorf((cy - 0.5f) / s + 0.5f); rs = min(max(rs, 0), W - 1);
    const float tx = ex[cs] * 1e-7f, ty = ey[rs] * 1e-7f;
    int clo = cs, chi = cs, rlo = rs, rhi = rs;
    while (clo > 0     && ex[clo - 1] >= tx) --clo;
    while (chi < W - 1 && ex[chi + 1] >= tx) ++chi;
    while (rlo > 0     && ey[rlo - 1] >= ty) --rlo;
    while (rhi < W - 1 && ey[rhi + 1] >= ty) ++rhi;
    sh_win[0] = clo; sh_win[1] = chi; sh_win[2] = rlo; sh_win[3] = rhi;
  }
  __syncthreads();

  const float inv = sh_inv;
  const int clo = sh_win[0], chi = sh_win[1], rlo = sh_win[2], rhi = sh_win[3];
  const size_t cbase = (size_t)(b * NC + t) * HW;   // t = channel
  float acc = 0.f;
  for (int r = rlo; r <= rhi; ++r) {
    float rowa = 0.f;
    for (int c = clo; c <= chi; ++c)
      rowa += ex[c] * ldf(feat, cbase + r * W + c, f32);
    acc += ey[r] * rowa;
  }
  tmpl_t[(((size_t)lvl * NB + b) * NC + t) * NN + n] = acc * inv;
}

// ---------------------------------------------------------------------------
// Kernel 2: cor[n,p] = sum_c tmpl[n,c]*feat[c,p]; class-max over n; writes the
// full FP32 output tile (feat copy folded into the c-loop load). Thread =
// pixel, 64 fp32 accumulators; tmpl read via wave-uniform addresses.
// ---------------------------------------------------------------------------
__global__ __launch_bounds__(256) void cor_kernel(
    const void* __restrict__ x0, const void* __restrict__ x1,
    const void* __restrict__ x2, const int* __restrict__ labels,
    const int* __restrict__ flag, const float* __restrict__ tmpl_t,
    float* __restrict__ out) {
  const int bx = blockIdx.x;           // 42 blocks: 32 | 8 | 2
  int lvl, rb;
  if (bx < 32)      { lvl = 0; rb = bx; }
  else if (bx < 40) { lvl = 1; rb = bx - 32; }
  else              { lvl = 2; rb = bx - 40; }
  const int W = 64 >> lvl, HW = W * W;
  const int tiles = HW >> 8;           // 256-pixel tiles per batch: 16,4,1
  const int b  = rb / tiles;
  const int pt = rb % tiles;
  const int p  = (pt << 8) + threadIdx.x;
  const void* feat = (lvl == 0) ? x0 : (lvl == 1) ? x1 : x2;
  const size_t base1 = (size_t)NB * (NC + NK) * 4096;            // 2179072
  const size_t base2 = base1 + (size_t)NB * (NC + NK) * 1024;    // 2723840
  const size_t lvl_base = (lvl == 0) ? 0 : (lvl == 1) ? base1 : base2;
  float* ob = out + lvl_base + (size_t)b * (NC + NK) * HW + p;
  const size_t fbase = (size_t)b * NC * HW + p;
  const float* tw = tmpl_t + ((size_t)lvl * NB + b) * NC * NN;
  const bool f32 = flag[0] != 0;

  __shared__ int lab[NN];
  if (threadIdx.x < NN) {
    const bool i64 = (labels[1] == 0);
    const int  m   = b * NN + threadIdx.x;
    lab[threadIdx.x] = i64 ? labels[2 * m] : labels[m];
  }
  __syncthreads();

  float acc[NN];
#pragma unroll
  for (int n = 0; n < NN; ++n) acc[n] = 0.f;

  auto fma_body = [&](int c, float f) {
    const float4* tc4 = (const float4*)(tw + c * NN);  // wave-uniform
#pragma unroll
    for (int j = 0; j < 16; ++j) {
      const float4 t4 = tc4[j];
      acc[4 * j + 0] += t4.x * f;
      acc[4 * j + 1] += t4.y * f;
      acc[4 * j + 2] += t4.z * f;
      acc[4 * j + 3] += t4.w * f;
    }
  };

  if (f32) {
    const float* pf = (const float*)feat + fbase;
    for (int c = 0; c < NC; ++c) {
      const float f = pf[(size_t)c * HW];
      ob[(size_t)c * HW] = f;                          // exact pass-through
      fma_body(c, f);
    }
  } else {
    const __hip_bfloat16* pb = (const __hip_bfloat16*)feat + fbase;
    for (int c = 0; c < NC; ++c) {
      const float f = __bfloat162float(pb[(size_t)c * HW]);
      ob[(size_t)c * HW] = f;
      fma_body(c, f);
    }
  }

  // class-wise max over n (invalid n contribute cor=0, correctly included)
#pragma unroll
  for (int k = 1; k <= NK; ++k) {
    float m = -FLT_MAX;
#pragma unroll
    for (int n = 0; n < NN; ++n)
      if (lab[n] == k) m = fmaxf(m, acc[n]);
    ob[(size_t)(NC + k - 1) * HW] = (m == -FLT_MAX ? 0.f : m);  // absent -> 0
  }
}

extern "C" void kernel_launch(void* const* d_in, const int* in_sizes, int n_in,
                              void* d_out, int out_size, void* d_ws, size_t ws_size,
                              hipStream_t stream) {
  const void* x0 = d_in[0];
  const void* x1 = d_in[1];
  const void* x2 = d_in[2];
  const void* ce = d_in[3];
  const int* idxp   = (const int*)d_in[4];
  const int* labels = (const int*)d_in[5];
  float* tmpl = (float*)d_ws;                        // 384 KiB
  int*   flag = (int*)((char*)d_ws + (size_t)TMPL_FLOATS * 4);
  float* out  = (float*)d_out;

  detect_kernel<<<1, 256, 0, stream>>>((const unsigned short*)d_in[0], flag);
  tmpl_kernel<<<3 * NB * NN, 256, 0, stream>>>(x0, x1, x2, ce, idxp, labels, flag, tmpl);
  cor_kernel<<<42, 256, 0, stream>>>(x0, x1, x2, labels, flag, tmpl, out);
}

// Round 4
// 184.993 us; speedup vs baseline: 1.0252x; 1.0252x over previous
//
#include <hip/hip_runtime.h>
#include <hip/hip_bf16.h>
#include <cfloat>
#include <cmath>

namespace {
constexpr int NB = 2;     // batch
constexpr int NN = 64;    // user inputs
constexpr int NC = 256;   // feature channels
constexpr int NK = 10;    // classes
constexpr float ALPHA = -1.0f / 18.0f;   // -0.5/sigma^2, sigma=3
constexpr int TMPL_FLOATS = 3 * NB * NC * NN;  // 98304 floats = 384 KiB
} // namespace

// load float input element i, runtime dtype (wave-uniform f32 flag)
__device__ __forceinline__ float ldf(const void* p, size_t i, bool f32) {
  return f32 ? ((const float*)p)[i]
             : __bfloat162float(((const __hip_bfloat16*)p)[i]);
}

// ---------------------------------------------------------------------------
// Kernel 0: fp32-vs-bf16 input sniff (R1 evidence: fp32; keep the hedge).
// ---------------------------------------------------------------------------
__global__ void detect_kernel(const unsigned short* __restrict__ x0w,
                              int* __restrict__ flag) {
  __shared__ int bad;
  if (threadIdx.x == 0) bad = 0;
  __syncthreads();
  int local = 0;
  for (int i = threadIdx.x; i < 2048; i += 256) {
    const unsigned e = (x0w[i] >> 7) & 0xFF;   // bf16 exponent field
    if (e >= 137) local = 1;                   // |v|>=1024, inf, NaN
  }
  if (local) atomicOr(&bad, 1);
  __syncthreads();
  if (threadIdx.x == 0) flag[0] = bad;         // 1 = fp32 inputs
}

// ---------------------------------------------------------------------------
// Kernel 1 (v2): per (level,b,n) template tmpl[c] = sum_wp h[wp]*feat[c,wp].
// lane = window pixel (Gaussian support <= 5x5 = 25 lanes; rel cutoff 1e-7),
// wave = 64-channel chunk. Coalesced window loads + butterfly reduce.
// Output layout [lvl][b][c][n] (n contiguous) for cor's scalar reads.
// ---------------------------------------------------------------------------
__global__ __launch_bounds__(256) void tmpl_kernel(
    const void* __restrict__ x0, const void* __restrict__ x1,
    const void* __restrict__ x2, const void* __restrict__ centers,
    const int* __restrict__ idxp, const int* __restrict__ labels,
    const int* __restrict__ flag, float* __restrict__ tmpl_t) {
  const int bx  = blockIdx.x;          // 3*NB*NN = 384 blocks
  const int lvl = bx >> 7;
  const int b   = (bx >> 6) & 1;
  const int n   = bx & 63;
  const int W   = 64 >> lvl;           // 64,32,16
  const int HW  = W * W;
  const float s = (float)(8 << lvl);   // nearest-resize stride
  const void* feat = (lvl == 0) ? x0 : (lvl == 1) ? x1 : x2;
  const bool f32 = flag[0] != 0;

  __shared__ float ex[64], ey[64];
  __shared__ float sh_h[64];    // normalized weight per window lane
  __shared__ int   sh_off[64];  // pixel offset r*W+c per window lane
  __shared__ float sh_inv;
  __shared__ int   sh_win[4];

  const int t = threadIdx.x;
  const float cx = ldf(centers, (size_t)(b * NN + n) * 2 + 0, f32);
  const float cy = ldf(centers, (size_t)(b * NN + n) * 2 + 1, f32);

  if (t < W) {
    const float dx = (float)t * s + 0.5f - cx;
    const float dy = (float)t * s + 0.5f - cy;
    ex[t] = expf(ALPHA * dx * dx);
    ey[t] = expf(ALPHA * dy * dy);
  }
  __syncthreads();

  if (t == 0) {
    const bool i64 = (labels[1] == 0);            // int64 hedge
    const int  m   = b * NN + n;
    const int  iv  = i64 ? idxp[2 * m] : idxp[m];
    float Sx = 0.f, Sy = 0.f;
    for (int i = 0; i < W; ++i) { Sx += ex[i]; Sy += ey[i]; }
    sh_inv = (iv != -1) ? 1.0f / (Sx * Sy + 1e-8f) : 0.0f;
    int cs = (int)floorf((cx - 0.5f) / s + 0.5f); cs = min(max(cs, 0), W - 1);
    int rs = (int)floorf((cy - 0.5f) / s + 0.5f); rs = min(max(rs, 0), W - 1);
    const float tx = ex[cs] * 1e-7f, ty = ey[rs] * 1e-7f;
    int clo = cs, chi = cs, rlo = rs, rhi = rs;
    while (clo > 0     && ex[clo - 1] >= tx) --clo;
    while (chi < W - 1 && ex[chi + 1] >= tx) ++chi;
    while (rlo > 0     && ey[rlo - 1] >= ty) --rlo;
    while (rhi < W - 1 && ey[rhi + 1] >= ty) ++rhi;
    sh_win[0] = clo; sh_win[1] = chi; sh_win[2] = rlo; sh_win[3] = rhi;
  }
  __syncthreads();

  if (t < 64) {                          // build window table
    const int clo = sh_win[0], chi = sh_win[1], rlo = sh_win[2];
    const int rhi = sh_win[3];
    const int ww = chi - clo + 1, wh = rhi - rlo + 1, wlen = ww * wh;
    const int use = min(t, wlen - 1);
    const int wr = use / ww, wc = use - wr * ww;
    sh_off[t] = (rlo + wr) * W + (clo + wc);
    sh_h[t]   = (t < wlen) ? ex[clo + wc] * ey[rlo + wr] * sh_inv : 0.f;
  }
  __syncthreads();

  const int wave = t >> 6, lane = t & 63;
  const float h  = sh_h[lane];
  const int  off = sh_off[lane];
  const size_t cb = (size_t)b * NC * HW + off;
  float* dst = tmpl_t + ((size_t)(lvl * NB + b) * NC) * NN + n;

#pragma unroll 4
  for (int i = 0; i < 64; ++i) {
    const int c = wave * 64 + i;
    float v = h * ldf(feat, cb + (size_t)c * HW, f32);
#pragma unroll
    for (int d = 1; d < 64; d <<= 1) v += __shfl_xor(v, d, 64);
    if (lane == 0) dst[(size_t)c * NN] = v;
  }
}

// ---------------------------------------------------------------------------
// Kernel 2 (v2): block = 64-pixel tile; wave w = channels [64w,64w+64).
// Each wave: 64 c-iters of {coalesced feat load -> out copy -> 64 FMA with
// wave-uniform tmpl[c][n] (scalar loads)}. Waves 1-3 dump acc to LDS; wave 0
// reduces, class-maxes over n, writes the 10 cor channels. 168 blocks.
// ---------------------------------------------------------------------------
__global__ __launch_bounds__(256) void cor_kernel(
    const void* __restrict__ x0, const void* __restrict__ x1,
    const void* __restrict__ x2, const int* __restrict__ labels,
    const int* __restrict__ flag, const float* __restrict__ tmpl_t,
    float* __restrict__ out) {
  const int bx = blockIdx.x;           // 168 blocks: 128 | 32 | 8
  int lvl, b, tile;
  if (bx < 128)      { lvl = 0; b = bx >> 6;  tile = bx & 63; }
  else if (bx < 160) { const int l = bx - 128; lvl = 1; b = l >> 4; tile = l & 15; }
  else               { const int l = bx - 160; lvl = 2; b = l >> 2; tile = l & 3; }
  const int W = 64 >> lvl, HW = W * W;
  const int wave = threadIdx.x >> 6, lane = threadIdx.x & 63;
  const int p = tile * 64 + lane;
  const void* feat = (lvl == 0) ? x0 : (lvl == 1) ? x1 : x2;
  const size_t base1 = (size_t)NB * (NC + NK) * 4096;            // 2179072
  const size_t base2 = base1 + (size_t)NB * (NC + NK) * 1024;    // 2723840
  const size_t lvl_base = (lvl == 0) ? 0 : (lvl == 1) ? base1 : base2;
  float* ob = out + lvl_base + (size_t)b * (NC + NK) * HW + p;
  const size_t fb = (size_t)b * NC * HW + p;
  const float* tws = tmpl_t + (size_t)(lvl * NB + b) * NC * NN;  // [c][n]
  const bool f32 = flag[0] != 0;

  __shared__ float part[3][NN][64];    // 48 KiB: waves 1..3 partials
  __shared__ int lab[NN];
  if (threadIdx.x < NN) {
    const bool i64 = (labels[1] == 0);
    const int  m   = b * NN + threadIdx.x;
    lab[threadIdx.x] = i64 ? labels[2 * m] : labels[m];
  }
  __syncthreads();

  float acc[NN];
#pragma unroll
  for (int n = 0; n < NN; ++n) acc[n] = 0.f;

  auto fma_body = [&](int c, float f) {
    const float4* t4p = (const float4*)(tws + c * NN);  // wave-uniform
#pragma unroll
    for (int j = 0; j < 16; ++j) {
      const float4 t4 = t4p[j];
      acc[4 * j + 0] += t4.x * f;
      acc[4 * j + 1] += t4.y * f;
      acc[4 * j + 2] += t4.z * f;
      acc[4 * j + 3] += t4.w * f;
    }
  };

  if (f32) {
    const float* pf = (const float*)feat;
#pragma unroll 4
    for (int i = 0; i < 64; ++i) {
      const int c = wave * 64 + i;
      const float f = pf[fb + (size_t)c * HW];
      ob[(size_t)c * HW] = f;                          // feat pass-through
      fma_body(c, f);
    }
  } else {
    const __hip_bfloat16* pb = (const __hip_bfloat16*)feat;
#pragma unroll 4
    for (int i = 0; i < 64; ++i) {
      const int c = wave * 64 + i;
      const float f = __bfloat162float(pb[fb + (size_t)c * HW]);
      ob[(size_t)c * HW] = f;
      fma_body(c, f);
    }
  }

  if (wave > 0) {
#pragma unroll
    for (int n = 0; n < NN; ++n) part[wave - 1][n][lane] = acc[n];
  }
  __syncthreads();

  if (wave == 0) {
    float m[NK];
#pragma unroll
    for (int k = 0; k < NK; ++k) m[k] = -FLT_MAX;
#pragma unroll
    for (int n = 0; n < NN; ++n) {
      const float tot = acc[n] + part[0][n][lane] + part[1][n][lane]
                               + part[2][n][lane];
      const int k = lab[n];
#pragma unroll
      for (int kk = 1; kk <= NK; ++kk)
        if (k == kk) m[kk - 1] = fmaxf(m[kk - 1], tot);
    }
#pragma unroll
    for (int k = 0; k < NK; ++k)
      ob[(size_t)(NC + k) * HW] = (m[k] == -FLT_MAX) ? 0.f : m[k];
  }
}

extern "C" void kernel_launch(void* const* d_in, const int* in_sizes, int n_in,
                              void* d_out, int out_size, void* d_ws, size_t ws_size,
                              hipStream_t stream) {
  const void* x0 = d_in[0];
  const void* x1 = d_in[1];
  const void* x2 = d_in[2];
  const void* ce = d_in[3];
  const int* idxp   = (const int*)d_in[4];
  const int* labels = (const int*)d_in[5];
  float* tmpl = (float*)d_ws;                        // 384 KiB
  int*   flag = (int*)((char*)d_ws + (size_t)TMPL_FLOATS * 4);
  float* out  = (float*)d_out;

  detect_kernel<<<1, 256, 0, stream>>>((const unsigned short*)d_in[0], flag);
  tmpl_kernel<<<3 * NB * NN, 256, 0, stream>>>(x0, x1, x2, ce, idxp, labels, flag, tmpl);
  cor_kernel<<<168, 256, 0, stream>>>(x0, x1, x2, labels, flag, tmpl, out);
}

// Round 5
// 132.853 us; speedup vs baseline: 1.4276x; 1.3925x over previous
//
#include <hip/hip_runtime.h>
#include <hip/hip_bf16.h>
#include <cfloat>
#include <cmath>

namespace {
constexpr int NB = 2;     // batch
constexpr int NN = 64;    // user inputs
constexpr int NC = 256;   // feature channels
constexpr int NK = 10;    // classes
constexpr float ALPHA = -1.0f / 18.0f;   // -0.5/sigma^2, sigma=3
constexpr int TMPL_FLOATS = 3 * NB * NC * NN;  // 98304 floats = 384 KiB
} // namespace

// Wave-uniform fp32-vs-bf16 sniff on x0's first 2KB (256 halfwords/wave,
// identical for all waves). fp32 low halves are ~uniform bits -> exp>=137
// (|v|>=1024/inf/NaN) appears w.p. 1-1e-35; bf16 N(0,1) never has exp>=137.
__device__ __forceinline__ bool sniff_f32(const void* x0) {
  const ushort4 v = ((const ushort4*)x0)[threadIdx.x & 63];
  bool bad = (((v.x >> 7) & 0xFF) >= 137) | (((v.y >> 7) & 0xFF) >= 137) |
             (((v.z >> 7) & 0xFF) >= 137) | (((v.w >> 7) & 0xFF) >= 137);
  return __ballot(bad) != 0ULL;
}

// load float input element i, runtime dtype (wave-uniform f32 flag)
__device__ __forceinline__ float ldf(const void* p, size_t i, bool f32) {
  return f32 ? ((const float*)p)[i]
             : __bfloat162float(((const __hip_bfloat16*)p)[i]);
}

// ---------------------------------------------------------------------------
// Kernel 1 (v3 = v1 structure): per (level,b,n) template
// tmpl[c] = sum_p h[p]*feat[c,p], thread = channel, per-thread window loop
// (<=~25 independent loads). No wave reductions (v2's shuffle chains were a
// 43us regression). Output [lvl][b][c][n], n contiguous.
// ---------------------------------------------------------------------------
__global__ __launch_bounds__(256) void tmpl_kernel(
    const void* __restrict__ x0, const void* __restrict__ x1,
    const void* __restrict__ x2, const void* __restrict__ centers,
    const int* __restrict__ idxp, const int* __restrict__ labels,
    float* __restrict__ tmpl_t) {
  const bool f32 = sniff_f32(x0);
  const int bx  = blockIdx.x;          // 3*NB*NN = 384 blocks
  const int lvl = bx >> 7;
  const int b   = (bx >> 6) & 1;
  const int n   = bx & 63;
  const int W   = 64 >> lvl;           // 64,32,16
  const int HW  = W * W;
  const float s = (float)(8 << lvl);   // nearest-resize stride
  const void* feat = (lvl == 0) ? x0 : (lvl == 1) ? x1 : x2;

  __shared__ float ex[64], ey[64];
  __shared__ float sh_inv;
  __shared__ int   sh_win[4];

  const int t = threadIdx.x;
  const float cx = ldf(centers, (size_t)(b * NN + n) * 2 + 0, f32);
  const float cy = ldf(centers, (size_t)(b * NN + n) * 2 + 1, f32);

  if (t < W) {
    const float dx = (float)t * s + 0.5f - cx;
    const float dy = (float)t * s + 0.5f - cy;
    ex[t] = expf(ALPHA * dx * dx);
    ey[t] = expf(ALPHA * dy * dy);
  }
  __syncthreads();

  if (t == 0) {
    const bool i64 = (labels[1] == 0);            // int64 hedge
    const int  m   = b * NN + n;
    const int  iv  = i64 ? idxp[2 * m] : idxp[m];
    float Sx = 0.f, Sy = 0.f;
    for (int i = 0; i < W; ++i) { Sx += ex[i]; Sy += ey[i]; }
    sh_inv = (iv != -1) ? 1.0f / (Sx * Sy + 1e-8f) : 0.0f;
    int cs = (int)floorf((cx - 0.5f) / s + 0.5f); cs = min(max(cs, 0), W - 1);
    int rs = (int)floorf((cy - 0.5f) / s + 0.5f); rs = min(max(rs, 0), W - 1);
    const float tx = ex[cs] * 1e-7f, ty = ey[rs] * 1e-7f;
    int clo = cs, chi = cs, rlo = rs, rhi = rs;
    while (clo > 0     && ex[clo - 1] >= tx) --clo;
    while (chi < W - 1 && ex[chi + 1] >= tx) ++chi;
    while (rlo > 0     && ey[rlo - 1] >= ty) --rlo;
    while (rhi < W - 1 && ey[rhi + 1] >= ty) ++rhi;
    sh_win[0] = clo; sh_win[1] = chi; sh_win[2] = rlo; sh_win[3] = rhi;
  }
  __syncthreads();

  const float inv = sh_inv;
  const int clo = sh_win[0], chi = sh_win[1], rlo = sh_win[2], rhi = sh_win[3];
  const size_t cbase = (size_t)(b * NC + t) * HW;   // t = channel
  float acc = 0.f;
  for (int r = rlo; r <= rhi; ++r) {
    float rowa = 0.f;
    for (int c = clo; c <= chi; ++c)
      rowa += ex[c] * ldf(feat, cbase + r * W + c, f32);
    acc += ey[r] * rowa;
  }
  tmpl_t[(((size_t)lvl * NB + b) * NC + t) * NN + n] = acc * inv;
}

// ---------------------------------------------------------------------------
// Kernel 2 (v3): block = 64-pixel tile, wave wv = n-chunk [16wv,16wv+16).
// Thread = pixel, acc[16] only -> ~170 free VGPRs for load prefetch (the R4
// bottleneck was acc[64] blocking MLP; VALUBusy was 3.8%). Per c-iter:
// 1 coalesced feat load + 4 wave-uniform float4 tmpl loads + 16 FMA; feat
// pass-through store assigned to wave (c>>6). Class-max: per-wave over its
// 16 n -> 10KB LDS partials -> wave 0 combines. 168 blocks.
// ---------------------------------------------------------------------------
__global__ __launch_bounds__(256, 1) void cor_kernel(
    const void* __restrict__ x0, const void* __restrict__ x1,
    const void* __restrict__ x2, const int* __restrict__ labels,
    const float* __restrict__ tmpl_t, float* __restrict__ out) {
  const bool f32 = sniff_f32(x0);
  const int bx = blockIdx.x;           // 168 blocks: 128 | 32 | 8
  int lvl, b, tile;
  if (bx < 128)      { lvl = 0; b = bx >> 6;  tile = bx & 63; }
  else if (bx < 160) { const int l = bx - 128; lvl = 1; b = l >> 4; tile = l & 15; }
  else               { const int l = bx - 160; lvl = 2; b = l >> 2; tile = l & 3; }
  const int W = 64 >> lvl, HW = W * W;
  const int lane = threadIdx.x & 63;
  const int wv = __builtin_amdgcn_readfirstlane(threadIdx.x >> 6);  // uniform
  const int p = tile * 64 + lane;
  const void* feat = (lvl == 0) ? x0 : (lvl == 1) ? x1 : x2;
  const size_t base1 = (size_t)NB * (NC + NK) * 4096;            // 2179072
  const size_t base2 = base1 + (size_t)NB * (NC + NK) * 1024;    // 2723840
  const size_t lvl_base = (lvl == 0) ? 0 : (lvl == 1) ? base1 : base2;
  float* ob = out + lvl_base + (size_t)b * (NC + NK) * HW + p;
  const size_t fb = (size_t)b * NC * HW + p;
  // this wave's n-chunk: tmpl[c][16wv..16wv+16), stride NN per c
  const float* tw = tmpl_t + (size_t)(lvl * NB + b) * NC * NN + 16 * wv;

  __shared__ int   lab[NN];
  __shared__ float part[4][NK][64];    // 10 KiB
  if (threadIdx.x < NN) {
    const bool i64 = (labels[1] == 0);
    const int  m   = b * NN + threadIdx.x;
    lab[threadIdx.x] = i64 ? labels[2 * m] : labels[m];
  }
  __syncthreads();

  float acc[16];
#pragma unroll
  for (int i = 0; i < 16; ++i) acc[i] = 0.f;

  auto kloop = [&](auto* pf) {
#pragma unroll 4
    for (int c = 0; c < NC; ++c) {
      const float f = (float)pf[fb + (size_t)c * HW];
      if (wv == (c >> 6)) ob[(size_t)c * HW] = f;    // uniform branch
      const float4* t4p = (const float4*)(tw + c * NN);
#pragma unroll
      for (int j = 0; j < 4; ++j) {
        const float4 t4 = t4p[j];
        acc[4 * j + 0] += t4.x * f;
        acc[4 * j + 1] += t4.y * f;
        acc[4 * j + 2] += t4.z * f;
        acc[4 * j + 3] += t4.w * f;
      }
    }
  };
  if (f32) kloop((const float*)feat);
  else     kloop((const __hip_bfloat16*)feat);

  // per-wave class max over its 16 n (invalid n have cor=0, still included)
  float km[NK];
#pragma unroll
  for (int k = 0; k < NK; ++k) km[k] = -FLT_MAX;
#pragma unroll
  for (int i = 0; i < 16; ++i) {
    const int L = lab[16 * wv + i];
#pragma unroll
    for (int kk = 1; kk <= NK; ++kk)
      if (L == kk) km[kk - 1] = fmaxf(km[kk - 1], acc[i]);
  }
#pragma unroll
  for (int k = 0; k < NK; ++k) part[wv][k][lane] = km[k];
  __syncthreads();

  if (wv == 0) {
#pragma unroll
    for (int k = 0; k < NK; ++k) {
      const float m = fmaxf(fmaxf(part[0][k][lane], part[1][k][lane]),
                            fmaxf(part[2][k][lane], part[3][k][lane]));
      ob[(size_t)(NC + k) * HW] = (m == -FLT_MAX) ? 0.f : m;   // absent -> 0
    }
  }
}

extern "C" void kernel_launch(void* const* d_in, const int* in_sizes, int n_in,
                              void* d_out, int out_size, void* d_ws, size_t ws_size,
                              hipStream_t stream) {
  const void* x0 = d_in[0];
  const void* x1 = d_in[1];
  const void* x2 = d_in[2];
  const void* ce = d_in[3];
  const int* idxp   = (const int*)d_in[4];
  const int* labels = (const int*)d_in[5];
  float* tmpl = (float*)d_ws;                        // 384 KiB
  float* out  = (float*)d_out;

  tmpl_kernel<<<3 * NB * NN, 256, 0, stream>>>(x0, x1, x2, ce, idxp, labels, tmpl);
  cor_kernel<<<168, 256, 0, stream>>>(x0, x1, x2, labels, tmpl, out);
}

// Round 6
// 109.331 us; speedup vs baseline: 1.7347x; 1.2152x over previous
//
#include <hip/hip_runtime.h>
#include <hip/hip_bf16.h>
#include <cfloat>
#include <cmath>

namespace {
constexpr int NB = 2;     // batch
constexpr int NN = 64;    // user inputs
constexpr int NC = 256;   // feature channels
constexpr int NK = 10;    // classes
constexpr float ALPHA = -1.0f / 18.0f;   // -0.5/sigma^2, sigma=3
constexpr int TMPL_FLOATS = 3 * NB * NC * NN;  // 98304 floats = 384 KiB
} // namespace

// Wave-uniform fp32-vs-bf16 sniff on x0's first 2KB. fp32 low halves are
// ~uniform bits -> bf16-exp>=137 (|v|>=1024/inf/NaN) appears w.p. ~1;
// bf16 N(0,1) never has exp>=137.
__device__ __forceinline__ bool sniff_f32(const void* x0) {
  const ushort4 v = ((const ushort4*)x0)[threadIdx.x & 63];
  bool bad = (((v.x >> 7) & 0xFF) >= 137) | (((v.y >> 7) & 0xFF) >= 137) |
             (((v.z >> 7) & 0xFF) >= 137) | (((v.w >> 7) & 0xFF) >= 137);
  return __ballot(bad) != 0ULL;
}

// load float input element i, runtime dtype (wave-uniform f32 flag)
__device__ __forceinline__ float ldf(const void* p, size_t i, bool f32) {
  return f32 ? ((const float*)p)[i]
             : __bfloat162float(((const __hip_bfloat16*)p)[i]);
}

// ---------------------------------------------------------------------------
// Kernel 1 (unchanged v1 structure): per (level,b,n) template
// tmpl[c] = sum_p h[p]*feat[c,p], thread = channel, per-thread window loop.
// Output [lvl][b][c][n], n contiguous.
// ---------------------------------------------------------------------------
__global__ __launch_bounds__(256) void tmpl_kernel(
    const void* __restrict__ x0, const void* __restrict__ x1,
    const void* __restrict__ x2, const void* __restrict__ centers,
    const int* __restrict__ idxp, const int* __restrict__ labels,
    float* __restrict__ tmpl_t) {
  const bool f32 = sniff_f32(x0);
  const int bx  = blockIdx.x;          // 3*NB*NN = 384 blocks
  const int lvl = bx >> 7;
  const int b   = (bx >> 6) & 1;
  const int n   = bx & 63;
  const int W   = 64 >> lvl;           // 64,32,16
  const int HW  = W * W;
  const float s = (float)(8 << lvl);   // nearest-resize stride
  const void* feat = (lvl == 0) ? x0 : (lvl == 1) ? x1 : x2;

  __shared__ float ex[64], ey[64];
  __shared__ float sh_inv;
  __shared__ int   sh_win[4];

  const int t = threadIdx.x;
  const float cx = ldf(centers, (size_t)(b * NN + n) * 2 + 0, f32);
  const float cy = ldf(centers, (size_t)(b * NN + n) * 2 + 1, f32);

  if (t < W) {
    const float dx = (float)t * s + 0.5f - cx;
    const float dy = (float)t * s + 0.5f - cy;
    ex[t] = expf(ALPHA * dx * dx);
    ey[t] = expf(ALPHA * dy * dy);
  }
  __syncthreads();

  if (t == 0) {
    const bool i64 = (labels[1] == 0);            // int64 hedge
    const int  m   = b * NN + n;
    const int  iv  = i64 ? idxp[2 * m] : idxp[m];
    float Sx = 0.f, Sy = 0.f;
    for (int i = 0; i < W; ++i) { Sx += ex[i]; Sy += ey[i]; }
    sh_inv = (iv != -1) ? 1.0f / (Sx * Sy + 1e-8f) : 0.0f;
    int cs = (int)floorf((cx - 0.5f) / s + 0.5f); cs = min(max(cs, 0), W - 1);
    int rs = (int)floorf((cy - 0.5f) / s + 0.5f); rs = min(max(rs, 0), W - 1);
    const float tx = ex[cs] * 1e-7f, ty = ey[rs] * 1e-7f;
    int clo = cs, chi = cs, rlo = rs, rhi = rs;
    while (clo > 0     && ex[clo - 1] >= tx) --clo;
    while (chi < W - 1 && ex[chi + 1] >= tx) ++chi;
    while (rlo > 0     && ey[rlo - 1] >= ty) --rlo;
    while (rhi < W - 1 && ey[rhi + 1] >= ty) ++rhi;
    sh_win[0] = clo; sh_win[1] = chi; sh_win[2] = rlo; sh_win[3] = rhi;
  }
  __syncthreads();

  const float inv = sh_inv;
  const int clo = sh_win[0], chi = sh_win[1], rlo = sh_win[2], rhi = sh_win[3];
  const size_t cbase = (size_t)(b * NC + t) * HW;   // t = channel
  float acc = 0.f;
  for (int r = rlo; r <= rhi; ++r) {
    float rowa = 0.f;
    for (int c = clo; c <= chi; ++c)
      rowa += ex[c] * ldf(feat, cbase + r * W + c, f32);
    acc += ey[r] * rowa;
  }
  tmpl_t[(((size_t)lvl * NB + b) * NC + t) * NN + n] = acc * inv;
}

// ---------------------------------------------------------------------------
// Kernel 2 (v4): block = 64-pixel tile, 1024 threads = 16 waves =
// 4 n-chunks x 4 c-quarters. R5 evidence: 672 waves (0.65/SIMD) can't hide
// ~490cyc/iter load latency; v4 gives 2688 waves and 64-iter chains.
// Per wave: 64 c-iters of {coalesced feat load (+pass-through store on
// nch==0) + 4 wave-uniform float4 tmpl loads + 16 FMA}. Partials combined
// via 64KB LDS, then per-n-chunk class-max, then final max. 168 blocks.
// ---------------------------------------------------------------------------
__global__ __launch_bounds__(1024, 1) void cor_kernel(
    const void* __restrict__ x0, const void* __restrict__ x1,
    const void* __restrict__ x2, const int* __restrict__ labels,
    const float* __restrict__ tmpl_t, float* __restrict__ out) {
  const bool f32 = sniff_f32(x0);
  const int bx = blockIdx.x;           // 168 blocks: 128 | 32 | 8
  int lvl, b, tile;
  if (bx < 128)      { lvl = 0; b = bx >> 6;  tile = bx & 63; }
  else if (bx < 160) { const int l = bx - 128; lvl = 1; b = l >> 4; tile = l & 15; }
  else               { const int l = bx - 160; lvl = 2; b = l >> 2; tile = l & 3; }
  const int W = 64 >> lvl, HW = W * W;
  const int lane = threadIdx.x & 63;
  const int wv  = __builtin_amdgcn_readfirstlane(threadIdx.x >> 6); // 0..15
  const int nch = wv & 3;              // n-chunk [16nch, 16nch+16)
  const int cq  = wv >> 2;             // c-quarter [64cq, 64cq+64)
  const int p = tile * 64 + lane;
  const void* feat = (lvl == 0) ? x0 : (lvl == 1) ? x1 : x2;
  const size_t base1 = (size_t)NB * (NC + NK) * 4096;            // 2179072
  const size_t base2 = base1 + (size_t)NB * (NC + NK) * 1024;    // 2723840
  const size_t lvl_base = (lvl == 0) ? 0 : (lvl == 1) ? base1 : base2;
  float* ob = out + lvl_base + (size_t)b * (NC + NK) * HW + p;
  const size_t fb = (size_t)b * NC * HW + p;
  // this wave's tmpl rows: [c][16nch..16nch+16), stride NN per c
  const float* tw = tmpl_t + (size_t)(lvl * NB + b) * NC * NN + 16 * nch;

  __shared__ float part[4][NN][64];    // 64 KiB: [cq][n][px]
  __shared__ float kmb[4][NK][64];     // 10 KiB: [nch][k][px]
  __shared__ int   lab[NN];
  if (threadIdx.x < NN) {
    const bool i64 = (labels[1] == 0);
    const int  m   = b * NN + threadIdx.x;
    lab[threadIdx.x] = i64 ? labels[2 * m] : labels[m];
  }

  float acc[16];
#pragma unroll
  for (int i = 0; i < 16; ++i) acc[i] = 0.f;

  auto kloop = [&](auto* pf) {
#pragma unroll 8
    for (int i = 0; i < 64; ++i) {
      const int c = cq * 64 + i;
      const float f = (float)pf[fb + (size_t)c * HW];
      if (nch == 0) ob[(size_t)c * HW] = f;     // pass-through, once per c
      const float4* t4p = (const float4*)(tw + c * NN);
#pragma unroll
      for (int j = 0; j < 4; ++j) {
        const float4 t4 = t4p[j];
        acc[4 * j + 0] += t4.x * f;
        acc[4 * j + 1] += t4.y * f;
        acc[4 * j + 2] += t4.z * f;
        acc[4 * j + 3] += t4.w * f;
      }
    }
  };
  if (f32) kloop((const float*)feat);
  else     kloop((const __hip_bfloat16*)feat);

#pragma unroll
  for (int i = 0; i < 16; ++i) part[cq][16 * nch + i][lane] = acc[i];
  __syncthreads();

  // waves with cq==0: sum c-quarters for their n-chunk, class-max over 16 n
  if (cq == 0) {
    float km[NK];
#pragma unroll
    for (int k = 0; k < NK; ++k) km[k] = -FLT_MAX;
#pragma unroll
    for (int i = 0; i < 16; ++i) {
      const int n = 16 * nch + i;
      const float tot = part[0][n][lane] + part[1][n][lane]
                      + part[2][n][lane] + part[3][n][lane];
      const int L = lab[n];
#pragma unroll
      for (int kk = 1; kk <= NK; ++kk)
        if (L == kk) km[kk - 1] = fmaxf(km[kk - 1], tot);
    }
#pragma unroll
    for (int k = 0; k < NK; ++k) kmb[nch][k][lane] = km[k];
  }
  __syncthreads();

  if (wv == 0) {
#pragma unroll
    for (int k = 0; k < NK; ++k) {
      const float m = fmaxf(fmaxf(kmb[0][k][lane], kmb[1][k][lane]),
                            fmaxf(kmb[2][k][lane], kmb[3][k][lane]));
      ob[(size_t)(NC + k) * HW] = (m == -FLT_MAX) ? 0.f : m;   // absent -> 0
    }
  }
}

extern "C" void kernel_launch(void* const* d_in, const int* in_sizes, int n_in,
                              void* d_out, int out_size, void* d_ws, size_t ws_size,
                              hipStream_t stream) {
  const void* x0 = d_in[0];
  const void* x1 = d_in[1];
  const void* x2 = d_in[2];
  const void* ce = d_in[3];
  const int* idxp   = (const int*)d_in[4];
  const int* labels = (const int*)d_in[5];
  float* tmpl = (float*)d_ws;                        // 384 KiB
  float* out  = (float*)d_out;

  tmpl_kernel<<<3 * NB * NN, 256, 0, stream>>>(x0, x1, x2, ce, idxp, labels, tmpl);
  cor_kernel<<<168, 1024, 0, stream>>>(x0, x1, x2, labels, tmpl, out);
}

// Round 7
// 100.299 us; speedup vs baseline: 1.8909x; 1.0900x over previous
//
#include <hip/hip_runtime.h>
#include <hip/hip_bf16.h>
#include <cfloat>
#include <cmath>

namespace {
constexpr int NB = 2;     // batch
constexpr int NN = 64;    // user inputs
constexpr int NC = 256;   // feature channels
constexpr int NK = 10;    // classes
constexpr float ALPHA = -1.0f / 18.0f;   // -0.5/sigma^2, sigma=3
constexpr int TMPL_FLOATS = 3 * NB * NC * NN;  // 98304 floats = 384 KiB
} // namespace

// Wave-uniform fp32-vs-bf16 sniff on x0's first 2KB. fp32 low halves are
// ~uniform bits -> bf16-exp>=137 (|v|>=1024/inf/NaN) appears w.p. ~1;
// bf16 N(0,1) never has exp>=137.
__device__ __forceinline__ bool sniff_f32(const void* x0) {
  const ushort4 v = ((const ushort4*)x0)[threadIdx.x & 63];
  bool bad = (((v.x >> 7) & 0xFF) >= 137) | (((v.y >> 7) & 0xFF) >= 137) |
             (((v.z >> 7) & 0xFF) >= 137) | (((v.w >> 7) & 0xFF) >= 137);
  return __ballot(bad) != 0ULL;
}

// load float input element i, runtime dtype (wave-uniform f32 flag)
__device__ __forceinline__ float ldf(const void* p, size_t i, bool f32) {
  return f32 ? ((const float*)p)[i]
             : __bfloat162float(((const __hip_bfloat16*)p)[i]);
}

// ---------------------------------------------------------------------------
// Kernel 1 (unchanged; est ~4us, never in top-5): per (level,b,n) template
// tmpl[c] = sum_p h[p]*feat[c,p], thread = channel, per-thread window loop.
// Output [lvl][b][c][n], n contiguous.
// ---------------------------------------------------------------------------
__global__ __launch_bounds__(256) void tmpl_kernel(
    const void* __restrict__ x0, const void* __restrict__ x1,
    const void* __restrict__ x2, const void* __restrict__ centers,
    const int* __restrict__ idxp, const int* __restrict__ labels,
    float* __restrict__ tmpl_t) {
  const bool f32 = sniff_f32(x0);
  const int bx  = blockIdx.x;          // 3*NB*NN = 384 blocks
  const int lvl = bx >> 7;
  const int b   = (bx >> 6) & 1;
  const int n   = bx & 63;
  const int W   = 64 >> lvl;           // 64,32,16
  const int HW  = W * W;
  const float s = (float)(8 << lvl);   // nearest-resize stride
  const void* feat = (lvl == 0) ? x0 : (lvl == 1) ? x1 : x2;

  __shared__ float ex[64], ey[64];
  __shared__ float sh_inv;
  __shared__ int   sh_win[4];

  const int t = threadIdx.x;
  const float cx = ldf(centers, (size_t)(b * NN + n) * 2 + 0, f32);
  const float cy = ldf(centers, (size_t)(b * NN + n) * 2 + 1, f32);

  if (t < W) {
    const float dx = (float)t * s + 0.5f - cx;
    const float dy = (float)t * s + 0.5f - cy;
    ex[t] = expf(ALPHA * dx * dx);
    ey[t] = expf(ALPHA * dy * dy);
  }
  __syncthreads();

  if (t == 0) {
    const bool i64 = (labels[1] == 0);            // int64 hedge
    const int  m   = b * NN + n;
    const int  iv  = i64 ? idxp[2 * m] : idxp[m];
    float Sx = 0.f, Sy = 0.f;
    for (int i = 0; i < W; ++i) { Sx += ex[i]; Sy += ey[i]; }
    sh_inv = (iv != -1) ? 1.0f / (Sx * Sy + 1e-8f) : 0.0f;
    int cs = (int)floorf((cx - 0.5f) / s + 0.5f); cs = min(max(cs, 0), W - 1);
    int rs = (int)floorf((cy - 0.5f) / s + 0.5f); rs = min(max(rs, 0), W - 1);
    const float tx = ex[cs] * 1e-7f, ty = ey[rs] * 1e-7f;
    int clo = cs, chi = cs, rlo = rs, rhi = rs;
    while (clo > 0     && ex[clo - 1] >= tx) --clo;
    while (chi < W - 1 && ex[chi + 1] >= tx) ++chi;
    while (rlo > 0     && ey[rlo - 1] >= ty) --rlo;
    while (rhi < W - 1 && ey[rhi + 1] >= ty) ++rhi;
    sh_win[0] = clo; sh_win[1] = chi; sh_win[2] = rlo; sh_win[3] = rhi;
  }
  __syncthreads();

  const float inv = sh_inv;
  const int clo = sh_win[0], chi = sh_win[1], rlo = sh_win[2], rhi = sh_win[3];
  const size_t cbase = (size_t)(b * NC + t) * HW;   // t = channel
  float acc = 0.f;
  for (int r = rlo; r <= rhi; ++r) {
    float rowa = 0.f;
    for (int c = clo; c <= chi; ++c)
      rowa += ex[c] * ldf(feat, cbase + r * W + c, f32);
    acc += ey[r] * rowa;
  }
  tmpl_t[(((size_t)lvl * NB + b) * NC + t) * NN + n] = acc * inv;
}

// ---------------------------------------------------------------------------
// Kernel 2 (v5): block = 64-pixel tile, 1024 threads = 16 waves =
// 4 n-chunks x 4 c-quarters. R6 fix: tmpl table (256x64 = 64KB) staged into
// LDS once per block, so the c-loop is {1 global feat load (depth-4 explicit
// prefetch) + 4 broadcast ds_read_b128 + 16 FMA} — removes the ~300cyc/iter
// VMEM dependency that kept cor at ~28us (VGPR=24 showed no compiler
// pipelining of the global tmpl loads). 168 blocks.
// ---------------------------------------------------------------------------
__global__ __launch_bounds__(1024, 1) void cor_kernel(
    const void* __restrict__ x0, const void* __restrict__ x1,
    const void* __restrict__ x2, const int* __restrict__ labels,
    const float* __restrict__ tmpl_t, float* __restrict__ out) {
  const bool f32 = sniff_f32(x0);
  const int bx = blockIdx.x;           // 168 blocks: 128 | 32 | 8
  int lvl, b, tile;
  if (bx < 128)      { lvl = 0; b = bx >> 6;  tile = bx & 63; }
  else if (bx < 160) { const int l = bx - 128; lvl = 1; b = l >> 4; tile = l & 15; }
  else               { const int l = bx - 160; lvl = 2; b = l >> 2; tile = l & 3; }
  const int W = 64 >> lvl, HW = W * W;
  const int lane = threadIdx.x & 63;
  const int wv  = __builtin_amdgcn_readfirstlane(threadIdx.x >> 6); // 0..15
  const int nch = wv & 3;              // n-chunk [16nch, 16nch+16)
  const int cq  = wv >> 2;             // c-quarter [64cq, 64cq+64)
  const int p = tile * 64 + lane;
  const void* feat = (lvl == 0) ? x0 : (lvl == 1) ? x1 : x2;
  const size_t base1 = (size_t)NB * (NC + NK) * 4096;            // 2179072
  const size_t base2 = base1 + (size_t)NB * (NC + NK) * 1024;    // 2723840
  const size_t lvl_base = (lvl == 0) ? 0 : (lvl == 1) ? base1 : base2;
  float* ob = out + lvl_base + (size_t)b * (NC + NK) * HW + p;
  const size_t fb = (size_t)b * NC * HW + p;

  __shared__ float tlds[NC][NN];       // 64 KiB: full tmpl table [c][n]
  __shared__ float part[4][NN][64];    // 64 KiB: [cq][n][px]
  __shared__ float kmb[4][NK][64];     // 10 KiB: [nch][k][px]
  __shared__ int   lab[NN];

  { // coalesced stage of the (lvl,b) tmpl slice: 16384 floats, float4 x4/thr
    const float4* src4 =
        (const float4*)(tmpl_t + (size_t)(lvl * NB + b) * NC * NN);
    float4* dst4 = (float4*)&tlds[0][0];
#pragma unroll
    for (int k = 0; k < 4; ++k)
      dst4[threadIdx.x + k * 1024] = src4[threadIdx.x + k * 1024];
  }
  if (threadIdx.x < NN) {
    const bool i64 = (labels[1] == 0);
    const int  m   = b * NN + threadIdx.x;
    lab[threadIdx.x] = i64 ? labels[2 * m] : labels[m];
  }
  __syncthreads();

  float acc[16];
#pragma unroll
  for (int i = 0; i < 16; ++i) acc[i] = 0.f;

  auto kloop = [&](auto* pf) {
    float fpre[4];                     // depth-4 feat prefetch
#pragma unroll
    for (int k = 0; k < 4; ++k)
      fpre[k] = (float)pf[fb + (size_t)(cq * 64 + k) * HW];
#pragma unroll 4
    for (int i = 0; i < 64; ++i) {
      const int c = cq * 64 + i;
      const float f = fpre[i & 3];
      const int cnx = min(c + 4, NC - 1);          // clamp: no OOB
      fpre[i & 3] = (float)pf[fb + (size_t)cnx * HW];
      if (nch == 0) ob[(size_t)c * HW] = f;        // pass-through, once per c
      const float4* t4p = (const float4*)&tlds[c][16 * nch];  // broadcast LDS
      const float4 t0 = t4p[0], t1 = t4p[1], t2 = t4p[2], t3 = t4p[3];
      acc[0]  += t0.x * f; acc[1]  += t0.y * f;
      acc[2]  += t0.z * f; acc[3]  += t0.w * f;
      acc[4]  += t1.x * f; acc[5]  += t1.y * f;
      acc[6]  += t1.z * f; acc[7]  += t1.w * f;
      acc[8]  += t2.x * f; acc[9]  += t2.y * f;
      acc[10] += t2.z * f; acc[11] += t2.w * f;
      acc[12] += t3.x * f; acc[13] += t3.y * f;
      acc[14] += t3.z * f; acc[15] += t3.w * f;
    }
  };
  if (f32) kloop((const float*)feat);
  else     kloop((const __hip_bfloat16*)feat);

#pragma unroll
  for (int i = 0; i < 16; ++i) part[cq][16 * nch + i][lane] = acc[i];
  __syncthreads();

  // waves with cq==0: sum c-quarters for their n-chunk, class-max over 16 n
  if (cq == 0) {
    float km[NK];
#pragma unroll
    for (int k = 0; k < NK; ++k) km[k] = -FLT_MAX;
#pragma unroll
    for (int i = 0; i < 16; ++i) {
      const int n = 16 * nch + i;
      const float tot = part[0][n][lane] + part[1][n][lane]
                      + part[2][n][lane] + part[3][n][lane];
      const int L = lab[n];
#pragma unroll
      for (int kk = 1; kk <= NK; ++kk)
        if (L == kk) km[kk - 1] = fmaxf(km[kk - 1], tot);
    }
#pragma unroll
    for (int k = 0; k < NK; ++k) kmb[nch][k][lane] = km[k];
  }
  __syncthreads();

  if (wv == 0) {
#pragma unroll
    for (int k = 0; k < NK; ++k) {
      const float m = fmaxf(fmaxf(kmb[0][k][lane], kmb[1][k][lane]),
                            fmaxf(kmb[2][k][lane], kmb[3][k][lane]));
      ob[(size_t)(NC + k) * HW] = (m == -FLT_MAX) ? 0.f : m;   // absent -> 0
    }
  }
}

extern "C" void kernel_launch(void* const* d_in, const int* in_sizes, int n_in,
                              void* d_out, int out_size, void* d_ws, size_t ws_size,
                              hipStream_t stream) {
  const void* x0 = d_in[0];
  const void* x1 = d_in[1];
  const void* x2 = d_in[2];
  const void* ce = d_in[3];
  const int* idxp   = (const int*)d_in[4];
  const int* labels = (const int*)d_in[5];
  float* tmpl = (float*)d_ws;                        // 384 KiB
  float* out  = (float*)d_out;

  tmpl_kernel<<<3 * NB * NN, 256, 0, stream>>>(x0, x1, x2, ce, idxp, labels, tmpl);
  cor_kernel<<<168, 1024, 0, stream>>>(x0, x1, x2, labels, tmpl, out);
}